// Round 8
// baseline (279.875 us; speedup 1.0000x reference)
//
#include <hip/hip_runtime.h>

// Problem constants: B=1, T=2048, D=2048, H=16, HD=128
#define TT 2048
#define DD 2048
#define NH 16
#define HDIM 128

typedef _Float16 half8 __attribute__((ext_vector_type(8)));
typedef _Float16 half4 __attribute__((ext_vector_type(4)));
typedef float floatx4 __attribute__((ext_vector_type(4)));

// ---------------------------------------------------------------------------
// Fused prep: z=0 -> straight fp32->f16 convert of x tile;
// z=1..4 -> W[K][N] fp32 -> f16 Wt[N][K] transpose+convert (32x32 LDS tile).
// ---------------------------------------------------------------------------
__global__ __launch_bounds__(256) void prep_kernel(const float* __restrict__ x,
                                                   const float* __restrict__ W1,
                                                   const float* __restrict__ W2,
                                                   const float* __restrict__ W3,
                                                   const float* __restrict__ W4,
                                                   _Float16* __restrict__ xh,
                                                   _Float16* __restrict__ O1,
                                                   _Float16* __restrict__ O2,
                                                   _Float16* __restrict__ O3,
                                                   _Float16* __restrict__ O4) {
    const int tx = threadIdx.x & 7;    // *4 cols
    const int ty = threadIdx.x >> 3;   // 0..31
    const int k0 = blockIdx.y * 32;
    const int n0 = blockIdx.x * 32;
    const int z = blockIdx.z;

    if (z == 0) {  // straight convert
        const float4 v = *(const float4*)(x + (size_t)(k0 + ty) * DD + n0 + tx * 4);
        half4 o;
        o[0] = (_Float16)v.x; o[1] = (_Float16)v.y;
        o[2] = (_Float16)v.z; o[3] = (_Float16)v.w;
        *(half4*)(xh + (size_t)(k0 + ty) * DD + n0 + tx * 4) = o;
        return;
    }
    const float* W = z == 1 ? W1 : (z == 2 ? W2 : (z == 3 ? W3 : W4));
    _Float16* O = z == 1 ? O1 : (z == 2 ? O2 : (z == 3 ? O3 : O4));
    __shared__ float T[32][33];
    const float4 v = *(const float4*)(W + (size_t)(k0 + ty) * DD + n0 + tx * 4);
    T[ty][tx * 4 + 0] = v.x;
    T[ty][tx * 4 + 1] = v.y;
    T[ty][tx * 4 + 2] = v.z;
    T[ty][tx * 4 + 3] = v.w;
    __syncthreads();
    half4 o;
    o[0] = (_Float16)T[tx * 4 + 0][ty];
    o[1] = (_Float16)T[tx * 4 + 1][ty];
    o[2] = (_Float16)T[tx * 4 + 2][ty];
    o[3] = (_Float16)T[tx * 4 + 3][ty];
    *(half4*)(O + (size_t)(n0 + ty) * DD + k0 + tx * 4) = o;
}

// ---------------------------------------------------------------------------
// MFMA f16 GEMM body (R0/R6-verified, the 62us/830TF structure at 3 blocks/CU).
// MODE: 0 = fp32 C[row][col], 1 = f16 C[row][col], 2 = f16 C[col][row].
// ---------------------------------------------------------------------------
template <int MODE>
__device__ __forceinline__ void hgemm_body(const _Float16* __restrict__ A,
                                           const _Float16* __restrict__ Bt,
                                           float* __restrict__ Cf,
                                           _Float16* __restrict__ Ch,
                                           const int row0, const int col0) {
    __shared__ __align__(16) _Float16 Al[128 * 32];
    __shared__ __align__(16) _Float16 Bl[128 * 32];

    const int tid = threadIdx.x;
    const int lane = tid & 63;
    const int w = tid >> 6;
    const int quad = lane >> 4;
    const int lr = lane & 15;
    const int wr = (w >> 1) * 64;
    const int wc = (w & 1) * 64;

    floatx4 acc[4][4];
#pragma unroll
    for (int i = 0; i < 4; ++i)
#pragma unroll
        for (int j = 0; j < 4; ++j)
            acc[i][j] = (floatx4){0.f, 0.f, 0.f, 0.f};

    const int subrow = lane >> 2;
    const int lblk = lane & 3;

    for (int k0 = 0; k0 < DD; k0 += 32) {
#pragma unroll
        for (int i = 0; i < 2; ++i) {
            const int ch = w * 2 + i;
            const int r = ch * 16 + subrow;
            const int gb = (lblk + (r >> 1)) & 3;
            const _Float16* ga = A + (size_t)(row0 + r) * DD + k0 + gb * 8;
            __builtin_amdgcn_global_load_lds(
                (const __attribute__((address_space(1))) void*)ga,
                (__attribute__((address_space(3))) void*)(Al + ch * 512), 16, 0, 0);
            const _Float16* gbp = Bt + (size_t)(col0 + r) * DD + k0 + gb * 8;
            __builtin_amdgcn_global_load_lds(
                (const __attribute__((address_space(1))) void*)gbp,
                (__attribute__((address_space(3))) void*)(Bl + ch * 512), 16, 0, 0);
        }
        __syncthreads();

        half8 af[4], bf[4];
#pragma unroll
        for (int i = 0; i < 4; ++i) {
            const int r = wr + i * 16 + lr;
            const int lb = (quad - (r >> 1)) & 3;
            af[i] = *(const half8*)&Al[r * 32 + lb * 8];
        }
#pragma unroll
        for (int j = 0; j < 4; ++j) {
            const int r = wc + j * 16 + lr;
            const int lb = (quad - (r >> 1)) & 3;
            bf[j] = *(const half8*)&Bl[r * 32 + lb * 8];
        }
#pragma unroll
        for (int i = 0; i < 4; ++i)
#pragma unroll
            for (int j = 0; j < 4; ++j)
                acc[i][j] = __builtin_amdgcn_mfma_f32_16x16x32_f16(af[i], bf[j], acc[i][j], 0, 0, 0);
        __syncthreads();
    }

    // epilogue: C/D layout col = lane&15, row = quad*4 + reg
#pragma unroll
    for (int i = 0; i < 4; ++i)
#pragma unroll
        for (int j = 0; j < 4; ++j) {
            const int col = col0 + wc + j * 16 + lr;
#pragma unroll
            for (int r = 0; r < 4; ++r) {
                const int row = row0 + wr + i * 16 + quad * 4 + r;
                if (MODE == 0) Cf[(size_t)row * DD + col] = acc[i][j][r];
                if (MODE == 1) Ch[(size_t)row * DD + col] = (_Float16)acc[i][j][r];
                if (MODE == 2) Ch[(size_t)col * DD + row] = (_Float16)acc[i][j][r];
            }
        }
}

// QKV fused (R0-verified): z=0 -> Qh, z=1 -> Kh, z=2 -> Vt (transposed).
// 768 blocks = 3 blocks/CU -> cross-block MFMA/staging overlap.
__global__ __launch_bounds__(256) void qkv_gemm_kernel(const _Float16* __restrict__ xh,
                                                       const _Float16* __restrict__ Wqt,
                                                       const _Float16* __restrict__ Wkt,
                                                       const _Float16* __restrict__ Wvt,
                                                       _Float16* __restrict__ Qh,
                                                       _Float16* __restrict__ Kh,
                                                       _Float16* __restrict__ Vt) {
    const int row0 = blockIdx.y * 128, col0 = blockIdx.x * 128;
    if (blockIdx.z == 0)      hgemm_body<1>(xh, Wqt, nullptr, Qh, row0, col0);
    else if (blockIdx.z == 1) hgemm_body<1>(xh, Wkt, nullptr, Kh, row0, col0);
    else                      hgemm_body<2>(xh, Wvt, nullptr, Vt, row0, col0);
}

// ---------------------------------------------------------------------------
// ogemm R8: 128^2 tile (verified 16-MFMA/wave inner loop), K-SPLIT z=2.
// Each block does half the K range (16 K-steps); epilogue atomicAdd into a
// zeroed C. 512 blocks = 2 blocks/CU -> m114 cross-block overlap WITHOUT
// degrading the per-wave MFMA ratio (the R6 64x128 mistake). Exactly 2
// commutative fp32 contributions per element -> bit-deterministic.
// C is zeroed by hipMemsetAsync on the same stream (ordered before us).
// ---------------------------------------------------------------------------
__global__ __launch_bounds__(256) void ogemm_kernel(const _Float16* __restrict__ Ah,
                                                    const _Float16* __restrict__ Wot,
                                                    float* __restrict__ C) {
    __shared__ __align__(16) _Float16 Al[128 * 32];
    __shared__ __align__(16) _Float16 Bl[128 * 32];

    const int row0 = blockIdx.y * 128;
    const int col0 = blockIdx.x * 128;
    const int kbeg = blockIdx.z * (DD / 2);
    const int kend = kbeg + DD / 2;

    const int tid = threadIdx.x;
    const int lane = tid & 63;
    const int w = tid >> 6;
    const int quad = lane >> 4;
    const int lr = lane & 15;
    const int wr = (w >> 1) * 64;
    const int wc = (w & 1) * 64;

    floatx4 acc[4][4];
#pragma unroll
    for (int i = 0; i < 4; ++i)
#pragma unroll
        for (int j = 0; j < 4; ++j)
            acc[i][j] = (floatx4){0.f, 0.f, 0.f, 0.f};

    const int subrow = lane >> 2;
    const int lblk = lane & 3;

    for (int k0 = kbeg; k0 < kend; k0 += 32) {
#pragma unroll
        for (int i = 0; i < 2; ++i) {
            const int ch = w * 2 + i;
            const int r = ch * 16 + subrow;
            const int gb = (lblk + (r >> 1)) & 3;
            const _Float16* ga = Ah + (size_t)(row0 + r) * DD + k0 + gb * 8;
            __builtin_amdgcn_global_load_lds(
                (const __attribute__((address_space(1))) void*)ga,
                (__attribute__((address_space(3))) void*)(Al + ch * 512), 16, 0, 0);
            const _Float16* gbp = Wot + (size_t)(col0 + r) * DD + k0 + gb * 8;
            __builtin_amdgcn_global_load_lds(
                (const __attribute__((address_space(1))) void*)gbp,
                (__attribute__((address_space(3))) void*)(Bl + ch * 512), 16, 0, 0);
        }
        __syncthreads();

        half8 af[4], bf[4];
#pragma unroll
        for (int i = 0; i < 4; ++i) {
            const int r = wr + i * 16 + lr;
            const int lb = (quad - (r >> 1)) & 3;
            af[i] = *(const half8*)&Al[r * 32 + lb * 8];
        }
#pragma unroll
        for (int j = 0; j < 4; ++j) {
            const int r = wc + j * 16 + lr;
            const int lb = (quad - (r >> 1)) & 3;
            bf[j] = *(const half8*)&Bl[r * 32 + lb * 8];
        }
#pragma unroll
        for (int i = 0; i < 4; ++i)
#pragma unroll
            for (int j = 0; j < 4; ++j)
                acc[i][j] = __builtin_amdgcn_mfma_f32_16x16x32_f16(af[i], bf[j], acc[i][j], 0, 0, 0);
        __syncthreads();
    }

    // epilogue: atomicAdd partial sums (C pre-zeroed; 2 contributions/elem)
#pragma unroll
    for (int i = 0; i < 4; ++i)
#pragma unroll
        for (int j = 0; j < 4; ++j) {
            const int col = col0 + wc + j * 16 + lr;
#pragma unroll
            for (int r = 0; r < 4; ++r) {
                const int row = row0 + wr + i * 16 + quad * 4 + r;
                atomicAdd(&C[(size_t)row * DD + col], acc[i][j][r]);
            }
        }
}

// ---------------------------------------------------------------------------
// RoPE in-place on f16 Q and K (verified; fp32 math, one f16 rounding).
// ---------------------------------------------------------------------------
__global__ __launch_bounds__(256) void rope_f16_kernel(_Float16* __restrict__ Qh,
                                                       _Float16* __restrict__ Kh,
                                                       const float* __restrict__ sn,
                                                       const float* __restrict__ cs) {
    const int idx = blockIdx.x * 256 + threadIdx.x;  // T*16*16 threads
    const int i = (idx & 15) * 4;
    const int h = (idx >> 4) & 15;
    const int t = idx >> 8;
    const size_t base = (size_t)t * DD + h * HDIM + i;
    half4 qa = *(half4*)(Qh + base), qb = *(half4*)(Qh + base + 64);
    half4 ka = *(half4*)(Kh + base), kb = *(half4*)(Kh + base + 64);
    half4 qa2, qb2, ka2, kb2;
#pragma unroll
    for (int j = 0; j < 4; ++j) {
        const float s1 = sn[t * HDIM + i + j];
        const float c1 = cs[t * HDIM + i + j];
        const float s2 = sn[t * HDIM + i + 64 + j];
        const float c2 = cs[t * HDIM + i + 64 + j];
        qa2[j] = (_Float16)((float)qa[j] * c1 - (float)qb[j] * s1);
        qb2[j] = (_Float16)((float)qb[j] * c2 + (float)qa[j] * s2);
        ka2[j] = (_Float16)((float)ka[j] * c1 - (float)kb[j] * s1);
        kb2[j] = (_Float16)((float)kb[j] * c2 + (float)ka[j] * s2);
    }
    *(half4*)(Qh + base) = qa2;
    *(half4*)(Qh + base + 64) = qb2;
    *(half4*)(Kh + base) = ka2;
    *(half4*)(Kh + base + 64) = kb2;
}

// ---------------------------------------------------------------------------
// MFMA flash attention (R7-verified): KVBLK=64, K via chunk-rotated
// gload_lds, V reg-staged into 72-padded layout (2-way banks), 64-col
// softmax chains, setprio around MFMA clusters.
// ---------------------------------------------------------------------------
__global__ __launch_bounds__(256) void attn_kernel(const _Float16* __restrict__ Qh,
                                                   const _Float16* __restrict__ Kh,
                                                   const _Float16* __restrict__ Vt,
                                                   const int* __restrict__ doc_ids,
                                                   _Float16* __restrict__ Aout) {
    __shared__ __align__(16) _Float16 Kl[64 * 128];    // 16KB (also reused as Ol)
    __shared__ __align__(16) _Float16 Vl[128 * 72];    // 18KB, padded stride 72
    __shared__ __align__(16) _Float16 Ps[4][16 * 72];  // per-wave P, padded
    __shared__ int sdoc[64];

    const int tid = threadIdx.x;
    const int lane = tid & 63;
    const int w = tid >> 6;
    const int quad = lane >> 4;
    const int lr = lane & 15;
    const int h = blockIdx.y;
    const int q0 = blockIdx.x * 64;

    // Q fragments (A-layout): row = q0 + w*16 + lr, k = c*32 + quad*8 + j
    const int qrow = q0 + w * 16 + lr;
    half8 qf[4];
#pragma unroll
    for (int c = 0; c < 4; ++c)
        qf[c] = *(const half8*)(Qh + (size_t)qrow * DD + h * HDIM + c * 32 + quad * 8);

    // docs of this lane's C-layout rows (quad*4 + r)
    int qd[4];
#pragma unroll
    for (int r = 0; r < 4; ++r)
        qd[r] = doc_ids[q0 + w * 16 + quad * 4 + r];

    float m_r[4], l_r[4];
    floatx4 Oacc[8];
#pragma unroll
    for (int r = 0; r < 4; ++r) { m_r[r] = -1e30f; l_r[r] = 0.f; }
#pragma unroll
    for (int n = 0; n < 8; ++n) Oacc[n] = (floatx4){0.f, 0.f, 0.f, 0.f};

    // binary search: first index with doc == doc_ids[q0]
    const int d0 = doc_ids[q0];
    int lo = 0, hi = q0;
    while (lo < hi) {
        const int mid = (lo + hi) >> 1;
        if (doc_ids[mid] < d0) lo = mid + 1; else hi = mid;
    }
    const int s_begin = lo & ~63;

    // V reg-staging coordinates: thread covers half a V row (4 x 16B)
    const int vrow = tid >> 1;            // 0..127 (d)
    const int vsc = (tid & 1) * 4;        // s-chunk base 0 or 4

    for (int s0 = s_begin; s0 < q0 + 64; s0 += 64) {
        // ---- stage K (chunk-rotated gload_lds): 16 chunks x 4 rows ----
#pragma unroll
        for (int i = 0; i < 4; ++i) {
            const int ch = w * 4 + i;
            const int r = ch * 4 + (lane >> 4);
            const int g = ((lane & 15) - r) & 15;
            const _Float16* src = Kh + (size_t)(s0 + r) * DD + h * HDIM + g * 8;
            __builtin_amdgcn_global_load_lds(
                (const __attribute__((address_space(1))) void*)src,
                (__attribute__((address_space(3))) void*)(Kl + ch * 512), 16, 0, 0);
        }
        // ---- stage V via regs into padded layout ----
        half8 vv[4];
#pragma unroll
        for (int ii = 0; ii < 4; ++ii)
            vv[ii] = *(const half8*)(Vt + (size_t)(h * HDIM + vrow) * TT + s0 + (vsc + ii) * 8);
        if (tid < 64) sdoc[tid] = doc_ids[s0 + tid];
#pragma unroll
        for (int ii = 0; ii < 4; ++ii)
            *(half8*)&Vl[vrow * 72 + (vsc + ii) * 8] = vv[ii];
        __syncthreads();

        // ---- S = Q K^T : four 16x16 col-blocks ----
        floatx4 S[4];
#pragma unroll
        for (int b = 0; b < 4; ++b) S[b] = (floatx4){0.f, 0.f, 0.f, 0.f};
        __builtin_amdgcn_s_setprio(1);
#pragma unroll
        for (int c = 0; c < 4; ++c) {
            const int p = (c * 4 + quad + lr) & 15;
#pragma unroll
            for (int b = 0; b < 4; ++b) {
                const half8 bb = *(const half8*)&Kl[(b * 16 + lr) * 128 + p * 8];
                S[b] = __builtin_amdgcn_mfma_f32_16x16x32_f16(qf[c], bb, S[b], 0, 0, 0);
            }
        }
        __builtin_amdgcn_s_setprio(0);

        // ---- mask + online softmax (C layout: col=lr, row=quad*4+r) ----
        const float scale = 0.08838834764831845f;
        float alpha[4];
#pragma unroll
        for (int r = 0; r < 4; ++r) {
            const int qg = q0 + w * 16 + quad * 4 + r;
            float x[4];
#pragma unroll
            for (int b = 0; b < 4; ++b) {
                const int sc = b * 16 + lr;
                const bool v = (s0 + sc <= qg) && (sdoc[sc] == qd[r]);
                x[b] = v ? S[b][r] * scale : -1e30f;
            }
            float m = fmaxf(fmaxf(x[0], x[1]), fmaxf(x[2], x[3]));
            m = fmaxf(m, __shfl_xor(m, 1));
            m = fmaxf(m, __shfl_xor(m, 2));
            m = fmaxf(m, __shfl_xor(m, 4));
            m = fmaxf(m, __shfl_xor(m, 8));
            const float mn = fmaxf(m_r[r], m);
            float e[4];
#pragma unroll
            for (int b = 0; b < 4; ++b) e[b] = __expf(x[b] - mn);
            float ts = (e[0] + e[1]) + (e[2] + e[3]);
            ts += __shfl_xor(ts, 1);
            ts += __shfl_xor(ts, 2);
            ts += __shfl_xor(ts, 4);
            ts += __shfl_xor(ts, 8);
            alpha[r] = __expf(m_r[r] - mn);
            l_r[r] = l_r[r] * alpha[r] + ts;
            m_r[r] = mn;
#pragma unroll
            for (int b = 0; b < 4; ++b)
                Ps[w][(quad * 4 + r) * 72 + b * 16 + lr] = (_Float16)e[b];
        }

        // ---- O = O*alpha + P V ----
#pragma unroll
        for (int n = 0; n < 8; ++n)
#pragma unroll
            for (int r = 0; r < 4; ++r) Oacc[n][r] *= alpha[r];

        const half8 af0 = *(const half8*)&Ps[w][lr * 72 + quad * 8];
        const half8 af1 = *(const half8*)&Ps[w][lr * 72 + 32 + quad * 8];
        __builtin_amdgcn_s_setprio(1);
#pragma unroll
        for (int n = 0; n < 8; ++n) {
            const half8 bv0 = *(const half8*)&Vl[(n * 16 + lr) * 72 + quad * 8];
            const half8 bv1 = *(const half8*)&Vl[(n * 16 + lr) * 72 + 32 + quad * 8];
            Oacc[n] = __builtin_amdgcn_mfma_f32_16x16x32_f16(af0, bv0, Oacc[n], 0, 0, 0);
            Oacc[n] = __builtin_amdgcn_mfma_f32_16x16x32_f16(af1, bv1, Oacc[n], 0, 0, 0);
        }
        __builtin_amdgcn_s_setprio(0);
        __syncthreads();
    }

    // ---- normalize, LDS round-trip for coalesced f16 store ----
    float inv[4];
#pragma unroll
    for (int r = 0; r < 4; ++r) inv[r] = 1.f / l_r[r];
    _Float16* Ol = Kl;  // reuse (all K reads fenced by loop-end barrier)
#pragma unroll
    for (int n = 0; n < 8; ++n)
#pragma unroll
        for (int r = 0; r < 4; ++r)
            Ol[(w * 16 + quad * 4 + r) * 128 + n * 16 + lr] = (_Float16)(Oacc[n][r] * inv[r]);
    __syncthreads();
#pragma unroll
    for (int it = 0; it < 4; ++it) {
        const int idx = tid + it * 256;
        const int row = idx >> 4, c8 = idx & 15;   // 64 rows x 16 half8 groups
        *(half8*)(Aout + (size_t)(q0 + row) * DD + h * HDIM + c8 * 8) =
            *(const half8*)&Ol[row * 128 + c8 * 8];
    }
}

// ---------------------------------------------------------------------------
// Launch: memset + 5 kernels. ws (f16, 4M elems = 8MB each): xh, Wqt, Wkt,
// Wvt, Wot, Qh, Kh, Vt = 64 MB. Attn output reuses xh.
// ---------------------------------------------------------------------------
extern "C" void kernel_launch(void* const* d_in, const int* in_sizes, int n_in,
                              void* d_out, int out_size, void* d_ws, size_t ws_size,
                              hipStream_t stream) {
    const float* x  = (const float*)d_in[0];
    const float* Wq = (const float*)d_in[1];
    const float* Wk = (const float*)d_in[2];
    const float* Wv = (const float*)d_in[3];
    const float* Wo = (const float*)d_in[4];
    const float* sn = (const float*)d_in[5];
    const float* cs = (const float*)d_in[6];
    const int* doc  = (const int*)d_in[7];
    float* out = (float*)d_out;

    const size_t NE = (size_t)TT * DD;
    _Float16* xh  = (_Float16*)d_ws;
    _Float16* Wqt = xh  + NE;
    _Float16* Wkt = Wqt + NE;
    _Float16* Wvt = Wkt + NE;
    _Float16* Wot = Wvt + NE;
    _Float16* Qh  = Wot + NE;
    _Float16* Kh  = Qh  + NE;
    _Float16* Vt  = Kh  + NE;
    _Float16* Abh = xh;  // reuse: xh consumed by qkv_gemm before attn writes

    const dim3 bb(256);

    prep_kernel<<<dim3(DD / 32, DD / 32, 5), bb, 0, stream>>>(x, Wq, Wk, Wv, Wo,
                                                              xh, Wqt, Wkt, Wvt, Wot);
    qkv_gemm_kernel<<<dim3(DD / 128, TT / 128, 3), bb, 0, stream>>>(xh, Wqt, Wkt, Wvt,
                                                                    Qh, Kh, Vt);
    rope_f16_kernel<<<dim3((TT * NH * 16) / 256), bb, 0, stream>>>(Qh, Kh, sn, cs);
    // zero C for the K-split atomic ogemm (ordered on-stream before ogemm)
    hipMemsetAsync(out, 0, NE * sizeof(float), stream);
    attn_kernel<<<dim3(TT / 64, NH), bb, 0, stream>>>(Qh, Kh, Vt, doc, Abh);
    ogemm_kernel<<<dim3(DD / 128, TT / 128, 2), bb, 0, stream>>>(Abh, Wot, out);
}

// Round 9
// 254.239 us; speedup vs baseline: 1.1008x; 1.1008x over previous
//
#include <hip/hip_runtime.h>

// Problem constants: B=1, T=2048, D=2048, H=16, HD=128
#define TT 2048
#define DD 2048
#define NH 16
#define HDIM 128

typedef _Float16 half8 __attribute__((ext_vector_type(8)));
typedef _Float16 half4 __attribute__((ext_vector_type(4)));
typedef float floatx4 __attribute__((ext_vector_type(4)));

// ---------------------------------------------------------------------------
// Fused prep R9: 64x64 tiles, wide accesses (G13).
// z=0 -> straight fp32->f16 convert of x (16 elems/thread, half8 stores);
// z=1..4 -> W[K][N] fp32 -> f16 Wt[N][K] transpose via 64x65 LDS tile.
// Wave-level: loads 256B/row-segment, stores 128B/row-segment contiguous.
// LDS store/read both 2-way max (65-word stride) = free (m136).
// ---------------------------------------------------------------------------
__global__ __launch_bounds__(256) void prep_kernel(const float* __restrict__ x,
                                                   const float* __restrict__ W1,
                                                   const float* __restrict__ W2,
                                                   const float* __restrict__ W3,
                                                   const float* __restrict__ W4,
                                                   _Float16* __restrict__ xh,
                                                   _Float16* __restrict__ O1,
                                                   _Float16* __restrict__ O2,
                                                   _Float16* __restrict__ O3,
                                                   _Float16* __restrict__ O4) {
    const int tx = threadIdx.x & 3;    // 16-float col chunk
    const int ty = threadIdx.x >> 2;   // 0..63 row
    const int r0 = blockIdx.y * 64;
    const int c0 = blockIdx.x * 64;
    const int z = blockIdx.z;

    if (z == 0) {  // straight convert: row r0+ty, cols c0+tx*16..+15
        const float* src = x + (size_t)(r0 + ty) * DD + c0 + tx * 16;
        const float4 v0 = ((const float4*)src)[0];
        const float4 v1 = ((const float4*)src)[1];
        const float4 v2 = ((const float4*)src)[2];
        const float4 v3 = ((const float4*)src)[3];
        half8 o0, o1;
        o0[0] = (_Float16)v0.x; o0[1] = (_Float16)v0.y;
        o0[2] = (_Float16)v0.z; o0[3] = (_Float16)v0.w;
        o0[4] = (_Float16)v1.x; o0[5] = (_Float16)v1.y;
        o0[6] = (_Float16)v1.z; o0[7] = (_Float16)v1.w;
        o1[0] = (_Float16)v2.x; o1[1] = (_Float16)v2.y;
        o1[2] = (_Float16)v2.z; o1[3] = (_Float16)v2.w;
        o1[4] = (_Float16)v3.x; o1[5] = (_Float16)v3.y;
        o1[6] = (_Float16)v3.z; o1[7] = (_Float16)v3.w;
        _Float16* dst = xh + (size_t)(r0 + ty) * DD + c0 + tx * 16;
        *(half8*)dst = o0;
        *(half8*)(dst + 8) = o1;
        return;
    }
    const float* W = z == 1 ? W1 : (z == 2 ? W2 : (z == 3 ? W3 : W4));
    _Float16* O = z == 1 ? O1 : (z == 2 ? O2 : (z == 3 ? O3 : O4));
    __shared__ float T[64][65];  // 16.6KB

    {   // load W tile: T[ty][col] = W[r0+ty][c0+col]
        const float* src = W + (size_t)(r0 + ty) * DD + c0 + tx * 16;
        const float4 v0 = ((const float4*)src)[0];
        const float4 v1 = ((const float4*)src)[1];
        const float4 v2 = ((const float4*)src)[2];
        const float4 v3 = ((const float4*)src)[3];
        float* t = &T[ty][tx * 16];
        ((float4*)t)[0] = v0;
        ((float4*)t)[1] = v1;
        ((float4*)t)[2] = v2;
        ((float4*)t)[3] = v3;
    }
    __syncthreads();

    // write transposed: O[c0+ty][r0 + tx*16 + j] = T[tx*16+j][ty]
    half8 o0, o1;
#pragma unroll
    for (int j = 0; j < 8; ++j) {
        o0[j] = (_Float16)T[tx * 16 + j][ty];
        o1[j] = (_Float16)T[tx * 16 + 8 + j][ty];
    }
    _Float16* dst = O + (size_t)(c0 + ty) * DD + r0 + tx * 16;
    *(half8*)dst = o0;
    *(half8*)(dst + 8) = o1;
}

// ---------------------------------------------------------------------------
// MFMA f16 GEMM body (R0/R6-verified, the 62us/830TF structure at 3 blocks/CU).
// MODE: 0 = fp32 C[row][col], 1 = f16 C[row][col], 2 = f16 C[col][row].
// ---------------------------------------------------------------------------
template <int MODE>
__device__ __forceinline__ void hgemm_body(const _Float16* __restrict__ A,
                                           const _Float16* __restrict__ Bt,
                                           float* __restrict__ Cf,
                                           _Float16* __restrict__ Ch,
                                           const int row0, const int col0) {
    __shared__ __align__(16) _Float16 Al[128 * 32];
    __shared__ __align__(16) _Float16 Bl[128 * 32];

    const int tid = threadIdx.x;
    const int lane = tid & 63;
    const int w = tid >> 6;
    const int quad = lane >> 4;
    const int lr = lane & 15;
    const int wr = (w >> 1) * 64;
    const int wc = (w & 1) * 64;

    floatx4 acc[4][4];
#pragma unroll
    for (int i = 0; i < 4; ++i)
#pragma unroll
        for (int j = 0; j < 4; ++j)
            acc[i][j] = (floatx4){0.f, 0.f, 0.f, 0.f};

    const int subrow = lane >> 2;
    const int lblk = lane & 3;

    for (int k0 = 0; k0 < DD; k0 += 32) {
#pragma unroll
        for (int i = 0; i < 2; ++i) {
            const int ch = w * 2 + i;
            const int r = ch * 16 + subrow;
            const int gb = (lblk + (r >> 1)) & 3;
            const _Float16* ga = A + (size_t)(row0 + r) * DD + k0 + gb * 8;
            __builtin_amdgcn_global_load_lds(
                (const __attribute__((address_space(1))) void*)ga,
                (__attribute__((address_space(3))) void*)(Al + ch * 512), 16, 0, 0);
            const _Float16* gbp = Bt + (size_t)(col0 + r) * DD + k0 + gb * 8;
            __builtin_amdgcn_global_load_lds(
                (const __attribute__((address_space(1))) void*)gbp,
                (__attribute__((address_space(3))) void*)(Bl + ch * 512), 16, 0, 0);
        }
        __syncthreads();

        half8 af[4], bf[4];
#pragma unroll
        for (int i = 0; i < 4; ++i) {
            const int r = wr + i * 16 + lr;
            const int lb = (quad - (r >> 1)) & 3;
            af[i] = *(const half8*)&Al[r * 32 + lb * 8];
        }
#pragma unroll
        for (int j = 0; j < 4; ++j) {
            const int r = wc + j * 16 + lr;
            const int lb = (quad - (r >> 1)) & 3;
            bf[j] = *(const half8*)&Bl[r * 32 + lb * 8];
        }
#pragma unroll
        for (int i = 0; i < 4; ++i)
#pragma unroll
            for (int j = 0; j < 4; ++j)
                acc[i][j] = __builtin_amdgcn_mfma_f32_16x16x32_f16(af[i], bf[j], acc[i][j], 0, 0, 0);
        __syncthreads();
    }

    // epilogue: C/D layout col = lane&15, row = quad*4 + reg
#pragma unroll
    for (int i = 0; i < 4; ++i)
#pragma unroll
        for (int j = 0; j < 4; ++j) {
            const int col = col0 + wc + j * 16 + lr;
#pragma unroll
            for (int r = 0; r < 4; ++r) {
                const int row = row0 + wr + i * 16 + quad * 4 + r;
                if (MODE == 0) Cf[(size_t)row * DD + col] = acc[i][j][r];
                if (MODE == 1) Ch[(size_t)row * DD + col] = (_Float16)acc[i][j][r];
                if (MODE == 2) Ch[(size_t)col * DD + row] = (_Float16)acc[i][j][r];
            }
        }
}

// QKV fused (R0-verified): z=0 -> Qh, z=1 -> Kh, z=2 -> Vt (transposed).
// 768 blocks = 3 blocks/CU -> cross-block MFMA/staging overlap.
__global__ __launch_bounds__(256) void qkv_gemm_kernel(const _Float16* __restrict__ xh,
                                                       const _Float16* __restrict__ Wqt,
                                                       const _Float16* __restrict__ Wkt,
                                                       const _Float16* __restrict__ Wvt,
                                                       _Float16* __restrict__ Qh,
                                                       _Float16* __restrict__ Kh,
                                                       _Float16* __restrict__ Vt) {
    const int row0 = blockIdx.y * 128, col0 = blockIdx.x * 128;
    if (blockIdx.z == 0)      hgemm_body<1>(xh, Wqt, nullptr, Qh, row0, col0);
    else if (blockIdx.z == 1) hgemm_body<1>(xh, Wkt, nullptr, Kh, row0, col0);
    else                      hgemm_body<2>(xh, Wvt, nullptr, Vt, row0, col0);
}

// ---------------------------------------------------------------------------
// ogemm 64x128 tile (R6/R7-verified config of the 256.1us best): 512 blocks
// = 2 blocks/CU. R8's K-split atomic variant regressed +24us -> reverted.
// ---------------------------------------------------------------------------
__global__ __launch_bounds__(256, 2) void ogemm_kernel(const _Float16* __restrict__ Ah,
                                                       const _Float16* __restrict__ Wot,
                                                       float* __restrict__ C) {
    __shared__ __align__(16) _Float16 Al[64 * 32];    // 4KB
    __shared__ __align__(16) _Float16 Bl[128 * 32];   // 8KB

    const int row0 = blockIdx.y * 64;
    const int col0 = blockIdx.x * 128;

    const int tid = threadIdx.x;
    const int lane = tid & 63;
    const int w = tid >> 6;            // 0..3
    const int quad = lane >> 4;
    const int lr = lane & 15;
    const int wr = (w >> 1) * 32;      // wave row base (2M)
    const int wc = (w & 1) * 64;       // wave col base (2N)

    floatx4 acc[2][4];
#pragma unroll
    for (int i = 0; i < 2; ++i)
#pragma unroll
        for (int j = 0; j < 4; ++j)
            acc[i][j] = (floatx4){0.f, 0.f, 0.f, 0.f};

    const int subrow = lane >> 2;
    const int lblk = lane & 3;

    for (int k0 = 0; k0 < DD; k0 += 32) {
        {
            const int ch = w;
            const int r = ch * 16 + subrow;
            const int gb = (lblk + (r >> 1)) & 3;
            const _Float16* ga = Ah + (size_t)(row0 + r) * DD + k0 + gb * 8;
            __builtin_amdgcn_global_load_lds(
                (const __attribute__((address_space(1))) void*)ga,
                (__attribute__((address_space(3))) void*)(Al + ch * 512), 16, 0, 0);
        }
#pragma unroll
        for (int i = 0; i < 2; ++i) {
            const int ch = w * 2 + i;
            const int r = ch * 16 + subrow;
            const int gb = (lblk + (r >> 1)) & 3;
            const _Float16* gbp = Wot + (size_t)(col0 + r) * DD + k0 + gb * 8;
            __builtin_amdgcn_global_load_lds(
                (const __attribute__((address_space(1))) void*)gbp,
                (__attribute__((address_space(3))) void*)(Bl + ch * 512), 16, 0, 0);
        }
        __syncthreads();

        half8 af[2], bf[4];
#pragma unroll
        for (int i = 0; i < 2; ++i) {
            const int r = wr + i * 16 + lr;
            const int lb = (quad - (r >> 1)) & 3;
            af[i] = *(const half8*)&Al[r * 32 + lb * 8];
        }
#pragma unroll
        for (int j = 0; j < 4; ++j) {
            const int r = wc + j * 16 + lr;
            const int lb = (quad - (r >> 1)) & 3;
            bf[j] = *(const half8*)&Bl[r * 32 + lb * 8];
        }
#pragma unroll
        for (int i = 0; i < 2; ++i)
#pragma unroll
            for (int j = 0; j < 4; ++j)
                acc[i][j] = __builtin_amdgcn_mfma_f32_16x16x32_f16(af[i], bf[j], acc[i][j], 0, 0, 0);
        __syncthreads();
    }

#pragma unroll
    for (int i = 0; i < 2; ++i)
#pragma unroll
        for (int j = 0; j < 4; ++j) {
            const int col = col0 + wc + j * 16 + lr;
#pragma unroll
            for (int r = 0; r < 4; ++r) {
                const int row = row0 + wr + i * 16 + quad * 4 + r;
                C[(size_t)row * DD + col] = acc[i][j][r];
            }
        }
}

// ---------------------------------------------------------------------------
// RoPE in-place on f16 Q and K (verified; fp32 math, one f16 rounding).
// ---------------------------------------------------------------------------
__global__ __launch_bounds__(256) void rope_f16_kernel(_Float16* __restrict__ Qh,
                                                       _Float16* __restrict__ Kh,
                                                       const float* __restrict__ sn,
                                                       const float* __restrict__ cs) {
    const int idx = blockIdx.x * 256 + threadIdx.x;  // T*16*16 threads
    const int i = (idx & 15) * 4;
    const int h = (idx >> 4) & 15;
    const int t = idx >> 8;
    const size_t base = (size_t)t * DD + h * HDIM + i;
    half4 qa = *(half4*)(Qh + base), qb = *(half4*)(Qh + base + 64);
    half4 ka = *(half4*)(Kh + base), kb = *(half4*)(Kh + base + 64);
    half4 qa2, qb2, ka2, kb2;
#pragma unroll
    for (int j = 0; j < 4; ++j) {
        const float s1 = sn[t * HDIM + i + j];
        const float c1 = cs[t * HDIM + i + j];
        const float s2 = sn[t * HDIM + i + 64 + j];
        const float c2 = cs[t * HDIM + i + 64 + j];
        qa2[j] = (_Float16)((float)qa[j] * c1 - (float)qb[j] * s1);
        qb2[j] = (_Float16)((float)qb[j] * c2 + (float)qa[j] * s2);
        ka2[j] = (_Float16)((float)ka[j] * c1 - (float)kb[j] * s1);
        kb2[j] = (_Float16)((float)kb[j] * c2 + (float)ka[j] * s2);
    }
    *(half4*)(Qh + base) = qa2;
    *(half4*)(Qh + base + 64) = qb2;
    *(half4*)(Kh + base) = ka2;
    *(half4*)(Kh + base + 64) = kb2;
}

// ---------------------------------------------------------------------------
// MFMA flash attention (R7-verified): KVBLK=64, K via chunk-rotated
// gload_lds, V reg-staged into 72-padded layout (2-way banks), 64-col
// softmax chains, setprio around MFMA clusters.
// ---------------------------------------------------------------------------
__global__ __launch_bounds__(256) void attn_kernel(const _Float16* __restrict__ Qh,
                                                   const _Float16* __restrict__ Kh,
                                                   const _Float16* __restrict__ Vt,
                                                   const int* __restrict__ doc_ids,
                                                   _Float16* __restrict__ Aout) {
    __shared__ __align__(16) _Float16 Kl[64 * 128];    // 16KB (also reused as Ol)
    __shared__ __align__(16) _Float16 Vl[128 * 72];    // 18KB, padded stride 72
    __shared__ __align__(16) _Float16 Ps[4][16 * 72];  // per-wave P, padded
    __shared__ int sdoc[64];

    const int tid = threadIdx.x;
    const int lane = tid & 63;
    const int w = tid >> 6;
    const int quad = lane >> 4;
    const int lr = lane & 15;
    const int h = blockIdx.y;
    const int q0 = blockIdx.x * 64;

    // Q fragments (A-layout): row = q0 + w*16 + lr, k = c*32 + quad*8 + j
    const int qrow = q0 + w * 16 + lr;
    half8 qf[4];
#pragma unroll
    for (int c = 0; c < 4; ++c)
        qf[c] = *(const half8*)(Qh + (size_t)qrow * DD + h * HDIM + c * 32 + quad * 8);

    // docs of this lane's C-layout rows (quad*4 + r)
    int qd[4];
#pragma unroll
    for (int r = 0; r < 4; ++r)
        qd[r] = doc_ids[q0 + w * 16 + quad * 4 + r];

    float m_r[4], l_r[4];
    floatx4 Oacc[8];
#pragma unroll
    for (int r = 0; r < 4; ++r) { m_r[r] = -1e30f; l_r[r] = 0.f; }
#pragma unroll
    for (int n = 0; n < 8; ++n) Oacc[n] = (floatx4){0.f, 0.f, 0.f, 0.f};

    // binary search: first index with doc == doc_ids[q0]
    const int d0 = doc_ids[q0];
    int lo = 0, hi = q0;
    while (lo < hi) {
        const int mid = (lo + hi) >> 1;
        if (doc_ids[mid] < d0) lo = mid + 1; else hi = mid;
    }
    const int s_begin = lo & ~63;

    // V reg-staging coordinates: thread covers half a V row (4 x 16B)
    const int vrow = tid >> 1;            // 0..127 (d)
    const int vsc = (tid & 1) * 4;        // s-chunk base 0 or 4

    for (int s0 = s_begin; s0 < q0 + 64; s0 += 64) {
        // ---- stage K (chunk-rotated gload_lds): 16 chunks x 4 rows ----
#pragma unroll
        for (int i = 0; i < 4; ++i) {
            const int ch = w * 4 + i;
            const int r = ch * 4 + (lane >> 4);
            const int g = ((lane & 15) - r) & 15;
            const _Float16* src = Kh + (size_t)(s0 + r) * DD + h * HDIM + g * 8;
            __builtin_amdgcn_global_load_lds(
                (const __attribute__((address_space(1))) void*)src,
                (__attribute__((address_space(3))) void*)(Kl + ch * 512), 16, 0, 0);
        }
        // ---- stage V via regs into padded layout ----
        half8 vv[4];
#pragma unroll
        for (int ii = 0; ii < 4; ++ii)
            vv[ii] = *(const half8*)(Vt + (size_t)(h * HDIM + vrow) * TT + s0 + (vsc + ii) * 8);
        if (tid < 64) sdoc[tid] = doc_ids[s0 + tid];
#pragma unroll
        for (int ii = 0; ii < 4; ++ii)
            *(half8*)&Vl[vrow * 72 + (vsc + ii) * 8] = vv[ii];
        __syncthreads();

        // ---- S = Q K^T : four 16x16 col-blocks ----
        floatx4 S[4];
#pragma unroll
        for (int b = 0; b < 4; ++b) S[b] = (floatx4){0.f, 0.f, 0.f, 0.f};
        __builtin_amdgcn_s_setprio(1);
#pragma unroll
        for (int c = 0; c < 4; ++c) {
            const int p = (c * 4 + quad + lr) & 15;
#pragma unroll
            for (int b = 0; b < 4; ++b) {
                const half8 bb = *(const half8*)&Kl[(b * 16 + lr) * 128 + p * 8];
                S[b] = __builtin_amdgcn_mfma_f32_16x16x32_f16(qf[c], bb, S[b], 0, 0, 0);
            }
        }
        __builtin_amdgcn_s_setprio(0);

        // ---- mask + online softmax (C layout: col=lr, row=quad*4+r) ----
        const float scale = 0.08838834764831845f;
        float alpha[4];
#pragma unroll
        for (int r = 0; r < 4; ++r) {
            const int qg = q0 + w * 16 + quad * 4 + r;
            float x[4];
#pragma unroll
            for (int b = 0; b < 4; ++b) {
                const int sc = b * 16 + lr;
                const bool v = (s0 + sc <= qg) && (sdoc[sc] == qd[r]);
                x[b] = v ? S[b][r] * scale : -1e30f;
            }
            float m = fmaxf(fmaxf(x[0], x[1]), fmaxf(x[2], x[3]));
            m = fmaxf(m, __shfl_xor(m, 1));
            m = fmaxf(m, __shfl_xor(m, 2));
            m = fmaxf(m, __shfl_xor(m, 4));
            m = fmaxf(m, __shfl_xor(m, 8));
            const float mn = fmaxf(m_r[r], m);
            float e[4];
#pragma unroll
            for (int b = 0; b < 4; ++b) e[b] = __expf(x[b] - mn);
            float ts = (e[0] + e[1]) + (e[2] + e[3]);
            ts += __shfl_xor(ts, 1);
            ts += __shfl_xor(ts, 2);
            ts += __shfl_xor(ts, 4);
            ts += __shfl_xor(ts, 8);
            alpha[r] = __expf(m_r[r] - mn);
            l_r[r] = l_r[r] * alpha[r] + ts;
            m_r[r] = mn;
#pragma unroll
            for (int b = 0; b < 4; ++b)
                Ps[w][(quad * 4 + r) * 72 + b * 16 + lr] = (_Float16)e[b];
        }

        // ---- O = O*alpha + P V ----
#pragma unroll
        for (int n = 0; n < 8; ++n)
#pragma unroll
            for (int r = 0; r < 4; ++r) Oacc[n][r] *= alpha[r];

        const half8 af0 = *(const half8*)&Ps[w][lr * 72 + quad * 8];
        const half8 af1 = *(const half8*)&Ps[w][lr * 72 + 32 + quad * 8];
        __builtin_amdgcn_s_setprio(1);
#pragma unroll
        for (int n = 0; n < 8; ++n) {
            const half8 bv0 = *(const half8*)&Vl[(n * 16 + lr) * 72 + quad * 8];
            const half8 bv1 = *(const half8*)&Vl[(n * 16 + lr) * 72 + 32 + quad * 8];
            Oacc[n] = __builtin_amdgcn_mfma_f32_16x16x32_f16(af0, bv0, Oacc[n], 0, 0, 0);
            Oacc[n] = __builtin_amdgcn_mfma_f32_16x16x32_f16(af1, bv1, Oacc[n], 0, 0, 0);
        }
        __builtin_amdgcn_s_setprio(0);
        __syncthreads();
    }

    // ---- normalize, LDS round-trip for coalesced f16 store ----
    float inv[4];
#pragma unroll
    for (int r = 0; r < 4; ++r) inv[r] = 1.f / l_r[r];
    _Float16* Ol = Kl;  // reuse (all K reads fenced by loop-end barrier)
#pragma unroll
    for (int n = 0; n < 8; ++n)
#pragma unroll
        for (int r = 0; r < 4; ++r)
            Ol[(w * 16 + quad * 4 + r) * 128 + n * 16 + lr] = (_Float16)(Oacc[n][r] * inv[r]);
    __syncthreads();
#pragma unroll
    for (int it = 0; it < 4; ++it) {
        const int idx = tid + it * 256;
        const int row = idx >> 4, c8 = idx & 15;   // 64 rows x 16 half8 groups
        *(half8*)(Aout + (size_t)(q0 + row) * DD + h * HDIM + c8 * 8) =
            *(const half8*)&Ol[row * 128 + c8 * 8];
    }
}

// ---------------------------------------------------------------------------
// Launch: 5 kernels. ws (f16, 4M elems = 8MB each): xh, Wqt, Wkt, Wvt, Wot,
// Qh, Kh, Vt = 64 MB. Attn output reuses xh (dead after qkv_gemm).
// ---------------------------------------------------------------------------
extern "C" void kernel_launch(void* const* d_in, const int* in_sizes, int n_in,
                              void* d_out, int out_size, void* d_ws, size_t ws_size,
                              hipStream_t stream) {
    const float* x  = (const float*)d_in[0];
    const float* Wq = (const float*)d_in[1];
    const float* Wk = (const float*)d_in[2];
    const float* Wv = (const float*)d_in[3];
    const float* Wo = (const float*)d_in[4];
    const float* sn = (const float*)d_in[5];
    const float* cs = (const float*)d_in[6];
    const int* doc  = (const int*)d_in[7];
    float* out = (float*)d_out;

    const size_t NE = (size_t)TT * DD;
    _Float16* xh  = (_Float16*)d_ws;
    _Float16* Wqt = xh  + NE;
    _Float16* Wkt = Wqt + NE;
    _Float16* Wvt = Wkt + NE;
    _Float16* Wot = Wvt + NE;
    _Float16* Qh  = Wot + NE;
    _Float16* Kh  = Qh  + NE;
    _Float16* Vt  = Kh  + NE;
    _Float16* Abh = xh;  // reuse: xh consumed by qkv_gemm before attn writes

    const dim3 bb(256);

    prep_kernel<<<dim3(DD / 64, DD / 64, 5), bb, 0, stream>>>(x, Wq, Wk, Wv, Wo,
                                                              xh, Wqt, Wkt, Wvt, Wot);
    qkv_gemm_kernel<<<dim3(DD / 128, TT / 128, 3), bb, 0, stream>>>(xh, Wqt, Wkt, Wvt,
                                                                    Qh, Kh, Vt);
    rope_f16_kernel<<<dim3((TT * NH * 16) / 256), bb, 0, stream>>>(Qh, Kh, sn, cs);
    attn_kernel<<<dim3(TT / 64, NH), bb, 0, stream>>>(Qh, Kh, Vt, doc, Abh);
    ogemm_kernel<<<dim3(DD / 128, TT / 64), bb, 0, stream>>>(Abh, Wot, out);
}

// Round 10
// 252.763 us; speedup vs baseline: 1.1073x; 1.0058x over previous
//
#include <hip/hip_runtime.h>

// Problem constants: B=1, T=2048, D=2048, H=16, HD=128
#define TT 2048
#define DD 2048
#define NH 16
#define HDIM 128

typedef _Float16 half8 __attribute__((ext_vector_type(8)));
typedef _Float16 half4 __attribute__((ext_vector_type(4)));
typedef float floatx4 __attribute__((ext_vector_type(4)));

// ---------------------------------------------------------------------------
// Fused prep (R9-verified): 64x64 tiles, wide accesses.
// z=0 -> straight fp32->f16 convert of x (16 elems/thread, half8 stores);
// z=1..4 -> W[K][N] fp32 -> f16 Wt[N][K] transpose via 64x65 LDS tile.
// ---------------------------------------------------------------------------
__global__ __launch_bounds__(256) void prep_kernel(const float* __restrict__ x,
                                                   const float* __restrict__ W1,
                                                   const float* __restrict__ W2,
                                                   const float* __restrict__ W3,
                                                   const float* __restrict__ W4,
                                                   _Float16* __restrict__ xh,
                                                   _Float16* __restrict__ O1,
                                                   _Float16* __restrict__ O2,
                                                   _Float16* __restrict__ O3,
                                                   _Float16* __restrict__ O4) {
    const int tx = threadIdx.x & 3;    // 16-float col chunk
    const int ty = threadIdx.x >> 2;   // 0..63 row
    const int r0 = blockIdx.y * 64;
    const int c0 = blockIdx.x * 64;
    const int z = blockIdx.z;

    if (z == 0) {  // straight convert: row r0+ty, cols c0+tx*16..+15
        const float* src = x + (size_t)(r0 + ty) * DD + c0 + tx * 16;
        const float4 v0 = ((const float4*)src)[0];
        const float4 v1 = ((const float4*)src)[1];
        const float4 v2 = ((const float4*)src)[2];
        const float4 v3 = ((const float4*)src)[3];
        half8 o0, o1;
        o0[0] = (_Float16)v0.x; o0[1] = (_Float16)v0.y;
        o0[2] = (_Float16)v0.z; o0[3] = (_Float16)v0.w;
        o0[4] = (_Float16)v1.x; o0[5] = (_Float16)v1.y;
        o0[6] = (_Float16)v1.z; o0[7] = (_Float16)v1.w;
        o1[0] = (_Float16)v2.x; o1[1] = (_Float16)v2.y;
        o1[2] = (_Float16)v2.z; o1[3] = (_Float16)v2.w;
        o1[4] = (_Float16)v3.x; o1[5] = (_Float16)v3.y;
        o1[6] = (_Float16)v3.z; o1[7] = (_Float16)v3.w;
        _Float16* dst = xh + (size_t)(r0 + ty) * DD + c0 + tx * 16;
        *(half8*)dst = o0;
        *(half8*)(dst + 8) = o1;
        return;
    }
    const float* W = z == 1 ? W1 : (z == 2 ? W2 : (z == 3 ? W3 : W4));
    _Float16* O = z == 1 ? O1 : (z == 2 ? O2 : (z == 3 ? O3 : O4));
    __shared__ float T[64][65];  // 16.6KB

    {   // load W tile: T[ty][col] = W[r0+ty][c0+col]
        const float* src = W + (size_t)(r0 + ty) * DD + c0 + tx * 16;
        const float4 v0 = ((const float4*)src)[0];
        const float4 v1 = ((const float4*)src)[1];
        const float4 v2 = ((const float4*)src)[2];
        const float4 v3 = ((const float4*)src)[3];
        float* t = &T[ty][tx * 16];
        ((float4*)t)[0] = v0;
        ((float4*)t)[1] = v1;
        ((float4*)t)[2] = v2;
        ((float4*)t)[3] = v3;
    }
    __syncthreads();

    // write transposed: O[c0+ty][r0 + tx*16 + j] = T[tx*16+j][ty]
    half8 o0, o1;
#pragma unroll
    for (int j = 0; j < 8; ++j) {
        o0[j] = (_Float16)T[tx * 16 + j][ty];
        o1[j] = (_Float16)T[tx * 16 + 8 + j][ty];
    }
    _Float16* dst = O + (size_t)(c0 + ty) * DD + r0 + tx * 16;
    *(half8*)dst = o0;
    *(half8*)(dst + 8) = o1;
}

// ---------------------------------------------------------------------------
// MFMA f16 GEMM body (R0/R6-verified, the 62us/830TF structure at 3 blocks/CU).
// MODE: 0 = fp32 C[row][col], 1 = f16 C[row][col], 2 = f16 C[col][row].
// ---------------------------------------------------------------------------
template <int MODE>
__device__ __forceinline__ void hgemm_body(const _Float16* __restrict__ A,
                                           const _Float16* __restrict__ Bt,
                                           float* __restrict__ Cf,
                                           _Float16* __restrict__ Ch,
                                           const int row0, const int col0) {
    __shared__ __align__(16) _Float16 Al[128 * 32];
    __shared__ __align__(16) _Float16 Bl[128 * 32];

    const int tid = threadIdx.x;
    const int lane = tid & 63;
    const int w = tid >> 6;
    const int quad = lane >> 4;
    const int lr = lane & 15;
    const int wr = (w >> 1) * 64;
    const int wc = (w & 1) * 64;

    floatx4 acc[4][4];
#pragma unroll
    for (int i = 0; i < 4; ++i)
#pragma unroll
        for (int j = 0; j < 4; ++j)
            acc[i][j] = (floatx4){0.f, 0.f, 0.f, 0.f};

    const int subrow = lane >> 2;
    const int lblk = lane & 3;

    for (int k0 = 0; k0 < DD; k0 += 32) {
#pragma unroll
        for (int i = 0; i < 2; ++i) {
            const int ch = w * 2 + i;
            const int r = ch * 16 + subrow;
            const int gb = (lblk + (r >> 1)) & 3;
            const _Float16* ga = A + (size_t)(row0 + r) * DD + k0 + gb * 8;
            __builtin_amdgcn_global_load_lds(
                (const __attribute__((address_space(1))) void*)ga,
                (__attribute__((address_space(3))) void*)(Al + ch * 512), 16, 0, 0);
            const _Float16* gbp = Bt + (size_t)(col0 + r) * DD + k0 + gb * 8;
            __builtin_amdgcn_global_load_lds(
                (const __attribute__((address_space(1))) void*)gbp,
                (__attribute__((address_space(3))) void*)(Bl + ch * 512), 16, 0, 0);
        }
        __syncthreads();

        half8 af[4], bf[4];
#pragma unroll
        for (int i = 0; i < 4; ++i) {
            const int r = wr + i * 16 + lr;
            const int lb = (quad - (r >> 1)) & 3;
            af[i] = *(const half8*)&Al[r * 32 + lb * 8];
        }
#pragma unroll
        for (int j = 0; j < 4; ++j) {
            const int r = wc + j * 16 + lr;
            const int lb = (quad - (r >> 1)) & 3;
            bf[j] = *(const half8*)&Bl[r * 32 + lb * 8];
        }
#pragma unroll
        for (int i = 0; i < 4; ++i)
#pragma unroll
            for (int j = 0; j < 4; ++j)
                acc[i][j] = __builtin_amdgcn_mfma_f32_16x16x32_f16(af[i], bf[j], acc[i][j], 0, 0, 0);
        __syncthreads();
    }

    // epilogue: C/D layout col = lane&15, row = quad*4 + reg
#pragma unroll
    for (int i = 0; i < 4; ++i)
#pragma unroll
        for (int j = 0; j < 4; ++j) {
            const int col = col0 + wc + j * 16 + lr;
#pragma unroll
            for (int r = 0; r < 4; ++r) {
                const int row = row0 + wr + i * 16 + quad * 4 + r;
                if (MODE == 0) Cf[(size_t)row * DD + col] = acc[i][j][r];
                if (MODE == 1) Ch[(size_t)row * DD + col] = (_Float16)acc[i][j][r];
                if (MODE == 2) Ch[(size_t)col * DD + row] = (_Float16)acc[i][j][r];
            }
        }
}

// QKV fused (R0-verified): z=0 -> Qh, z=1 -> Kh, z=2 -> Vt (transposed).
// 768 blocks = 3 blocks/CU -> cross-block MFMA/staging overlap.
__global__ __launch_bounds__(256) void qkv_gemm_kernel(const _Float16* __restrict__ xh,
                                                       const _Float16* __restrict__ Wqt,
                                                       const _Float16* __restrict__ Wkt,
                                                       const _Float16* __restrict__ Wvt,
                                                       _Float16* __restrict__ Qh,
                                                       _Float16* __restrict__ Kh,
                                                       _Float16* __restrict__ Vt) {
    const int row0 = blockIdx.y * 128, col0 = blockIdx.x * 128;
    if (blockIdx.z == 0)      hgemm_body<1>(xh, Wqt, nullptr, Qh, row0, col0);
    else if (blockIdx.z == 1) hgemm_body<1>(xh, Wkt, nullptr, Kh, row0, col0);
    else                      hgemm_body<2>(xh, Wvt, nullptr, Vt, row0, col0);
}

// ---------------------------------------------------------------------------
// ogemm 64x128 tile (R6/R7-verified config of the 254/256us best): 512 blocks
// = 2 blocks/CU.
// ---------------------------------------------------------------------------
__global__ __launch_bounds__(256, 2) void ogemm_kernel(const _Float16* __restrict__ Ah,
                                                       const _Float16* __restrict__ Wot,
                                                       float* __restrict__ C) {
    __shared__ __align__(16) _Float16 Al[64 * 32];    // 4KB
    __shared__ __align__(16) _Float16 Bl[128 * 32];   // 8KB

    const int row0 = blockIdx.y * 64;
    const int col0 = blockIdx.x * 128;

    const int tid = threadIdx.x;
    const int lane = tid & 63;
    const int w = tid >> 6;            // 0..3
    const int quad = lane >> 4;
    const int lr = lane & 15;
    const int wr = (w >> 1) * 32;      // wave row base (2M)
    const int wc = (w & 1) * 64;       // wave col base (2N)

    floatx4 acc[2][4];
#pragma unroll
    for (int i = 0; i < 2; ++i)
#pragma unroll
        for (int j = 0; j < 4; ++j)
            acc[i][j] = (floatx4){0.f, 0.f, 0.f, 0.f};

    const int subrow = lane >> 2;
    const int lblk = lane & 3;

    for (int k0 = 0; k0 < DD; k0 += 32) {
        {
            const int ch = w;
            const int r = ch * 16 + subrow;
            const int gb = (lblk + (r >> 1)) & 3;
            const _Float16* ga = Ah + (size_t)(row0 + r) * DD + k0 + gb * 8;
            __builtin_amdgcn_global_load_lds(
                (const __attribute__((address_space(1))) void*)ga,
                (__attribute__((address_space(3))) void*)(Al + ch * 512), 16, 0, 0);
        }
#pragma unroll
        for (int i = 0; i < 2; ++i) {
            const int ch = w * 2 + i;
            const int r = ch * 16 + subrow;
            const int gb = (lblk + (r >> 1)) & 3;
            const _Float16* gbp = Wot + (size_t)(col0 + r) * DD + k0 + gb * 8;
            __builtin_amdgcn_global_load_lds(
                (const __attribute__((address_space(1))) void*)gbp,
                (__attribute__((address_space(3))) void*)(Bl + ch * 512), 16, 0, 0);
        }
        __syncthreads();

        half8 af[2], bf[4];
#pragma unroll
        for (int i = 0; i < 2; ++i) {
            const int r = wr + i * 16 + lr;
            const int lb = (quad - (r >> 1)) & 3;
            af[i] = *(const half8*)&Al[r * 32 + lb * 8];
        }
#pragma unroll
        for (int j = 0; j < 4; ++j) {
            const int r = wc + j * 16 + lr;
            const int lb = (quad - (r >> 1)) & 3;
            bf[j] = *(const half8*)&Bl[r * 32 + lb * 8];
        }
#pragma unroll
        for (int i = 0; i < 2; ++i)
#pragma unroll
            for (int j = 0; j < 4; ++j)
                acc[i][j] = __builtin_amdgcn_mfma_f32_16x16x32_f16(af[i], bf[j], acc[i][j], 0, 0, 0);
        __syncthreads();
    }

#pragma unroll
    for (int i = 0; i < 2; ++i)
#pragma unroll
        for (int j = 0; j < 4; ++j) {
            const int col = col0 + wc + j * 16 + lr;
#pragma unroll
            for (int r = 0; r < 4; ++r) {
                const int row = row0 + wr + i * 16 + quad * 4 + r;
                C[(size_t)row * DD + col] = acc[i][j][r];
            }
        }
}

// ---------------------------------------------------------------------------
// MFMA flash attention R10: RoPE FUSED (rope kernel deleted).
//  - Q-rope: thread-local — qf[c] pairs with qf[c^2] (i and i+64 live in the
//    same thread's fragments). Applied once at the hoisted Q load.
//  - K-rope: reg-staged K (global->reg->rope->ds_write) writing the SAME
//    chunk-rotated layout slot=(G+r)&15 the verified QK^T read expects.
//    ds_write bank check: addr words = r*64+slot*4+[0..3], r*64%32=0 ->
//    8 accesses/bank = b128 structural minimum, conflict-free.
//  - V reg-staged into 72-padded layout (R7-verified), 64-col softmax chains,
//    setprio around MFMA clusters. Block = 4 waves, BQ=64, KVBLK=64.
// ---------------------------------------------------------------------------
__global__ __launch_bounds__(256) void attn_kernel(const _Float16* __restrict__ Qh,
                                                   const _Float16* __restrict__ Kh,
                                                   const _Float16* __restrict__ Vt,
                                                   const float* __restrict__ sn,
                                                   const float* __restrict__ cs,
                                                   const int* __restrict__ doc_ids,
                                                   _Float16* __restrict__ Aout) {
    __shared__ __align__(16) _Float16 Kl[64 * 128];    // 16KB (also reused as Ol)
    __shared__ __align__(16) _Float16 Vl[128 * 72];    // 18KB, padded stride 72
    __shared__ __align__(16) _Float16 Ps[4][16 * 72];  // per-wave P, padded
    __shared__ int sdoc[64];

    const int tid = threadIdx.x;
    const int lane = tid & 63;
    const int w = tid >> 6;
    const int quad = lane >> 4;
    const int lr = lane & 15;
    const int h = blockIdx.y;
    const int q0 = blockIdx.x * 64;

    // ---- Q fragments + fused RoPE (thread-local pairing c <-> c+2) ----
    const int qrow = q0 + w * 16 + lr;
    half8 qf[4];
#pragma unroll
    for (int c = 0; c < 4; ++c)
        qf[c] = *(const half8*)(Qh + (size_t)qrow * DD + h * HDIM + c * 32 + quad * 8);
#pragma unroll
    for (int c = 0; c < 2; ++c) {
        const int ib = c * 32 + quad * 8;
        const float* snp = sn + (size_t)qrow * HDIM + ib;
        const float* csp = cs + (size_t)qrow * HDIM + ib;
#pragma unroll
        for (int j = 0; j < 8; ++j) {
            const float s1 = snp[j], c1 = csp[j];
            const float s2 = snp[64 + j], c2 = csp[64 + j];
            const float lo = (float)qf[c][j], hi = (float)qf[c + 2][j];
            qf[c][j] = (_Float16)(lo * c1 - hi * s1);
            qf[c + 2][j] = (_Float16)(hi * c2 + lo * s2);
        }
    }

    // docs of this lane's C-layout rows (quad*4 + r)
    int qd[4];
#pragma unroll
    for (int r = 0; r < 4; ++r)
        qd[r] = doc_ids[q0 + w * 16 + quad * 4 + r];

    float m_r[4], l_r[4];
    floatx4 Oacc[8];
#pragma unroll
    for (int r = 0; r < 4; ++r) { m_r[r] = -1e30f; l_r[r] = 0.f; }
#pragma unroll
    for (int n = 0; n < 8; ++n) Oacc[n] = (floatx4){0.f, 0.f, 0.f, 0.f};

    // binary search: first index with doc == doc_ids[q0]
    const int d0 = doc_ids[q0];
    int lo_ = 0, hi_ = q0;
    while (lo_ < hi_) {
        const int mid = (lo_ + hi_) >> 1;
        if (doc_ids[mid] < d0) lo_ = mid + 1; else hi_ = mid;
    }
    const int s_begin = lo_ & ~63;

    // V reg-staging coordinates: thread covers half a V row (4 x 16B)
    const int vrow = tid >> 1;            // 0..127 (d)
    const int vsc = (tid & 1) * 4;        // s-chunk base 0 or 4

    // K reg-staging task coords: task tau -> row r = tau>>3, chunk-pair gp =
    // tau&7 (covers global chunks gp and gp+8 = rope partners i, i+64)
    const int kr0 = tid >> 3;             // batch 0 row (0..31)
    const int kgp = tid & 7;              // chunk pair

    for (int s0 = s_begin; s0 < q0 + 64; s0 += 64) {
        // ---- K loads (reg) ----
        half8 klo[2], khi[2];
#pragma unroll
        for (int b = 0; b < 2; ++b) {
            const int r = kr0 + b * 32;
            const _Float16* src = Kh + (size_t)(s0 + r) * DD + h * HDIM + kgp * 8;
            klo[b] = *(const half8*)src;
            khi[b] = *(const half8*)(src + 64);
        }
        // ---- V loads (reg) ----
        half8 vv[4];
#pragma unroll
        for (int ii = 0; ii < 4; ++ii)
            vv[ii] = *(const half8*)(Vt + (size_t)(h * HDIM + vrow) * TT + s0 + (vsc + ii) * 8);
        if (tid < 64) sdoc[tid] = doc_ids[s0 + tid];

        // ---- K rope + ds_write (chunk-rotated layout: slot = (G+r)&15) ----
#pragma unroll
        for (int b = 0; b < 2; ++b) {
            const int r = kr0 + b * 32;
            const int t = s0 + r;
            const float* snp = sn + (size_t)t * HDIM + kgp * 8;
            const float* csp = cs + (size_t)t * HDIM + kgp * 8;
            half8 olo, ohi;
#pragma unroll
            for (int j = 0; j < 8; ++j) {
                const float s1 = snp[j], c1 = csp[j];
                const float s2 = snp[64 + j], c2 = csp[64 + j];
                const float lo = (float)klo[b][j], hi = (float)khi[b][j];
                olo[j] = (_Float16)(lo * c1 - hi * s1);
                ohi[j] = (_Float16)(hi * c2 + lo * s2);
            }
            const int slo = (kgp + r) & 15;
            const int shi = (kgp + 8 + r) & 15;
            *(half8*)&Kl[r * 128 + slo * 8] = olo;
            *(half8*)&Kl[r * 128 + shi * 8] = ohi;
        }
        // ---- V writes (padded layout) ----
#pragma unroll
        for (int ii = 0; ii < 4; ++ii)
            *(half8*)&Vl[vrow * 72 + (vsc + ii) * 8] = vv[ii];
        __syncthreads();

        // ---- S = Q K^T : four 16x16 col-blocks ----
        floatx4 S[4];
#pragma unroll
        for (int b = 0; b < 4; ++b) S[b] = (floatx4){0.f, 0.f, 0.f, 0.f};
        __builtin_amdgcn_s_setprio(1);
#pragma unroll
        for (int c = 0; c < 4; ++c) {
            const int p = (c * 4 + quad + lr) & 15;
#pragma unroll
            for (int b = 0; b < 4; ++b) {
                const half8 bb = *(const half8*)&Kl[(b * 16 + lr) * 128 + p * 8];
                S[b] = __builtin_amdgcn_mfma_f32_16x16x32_f16(qf[c], bb, S[b], 0, 0, 0);
            }
        }
        __builtin_amdgcn_s_setprio(0);

        // ---- mask + online softmax (C layout: col=lr, row=quad*4+r) ----
        const float scale = 0.08838834764831845f;
        float alpha[4];
#pragma unroll
        for (int r = 0; r < 4; ++r) {
            const int qg = q0 + w * 16 + quad * 4 + r;
            float x[4];
#pragma unroll
            for (int b = 0; b < 4; ++b) {
                const int sc = b * 16 + lr;
                const bool v = (s0 + sc <= qg) && (sdoc[sc] == qd[r]);
                x[b] = v ? S[b][r] * scale : -1e30f;
            }
            float m = fmaxf(fmaxf(x[0], x[1]), fmaxf(x[2], x[3]));
            m = fmaxf(m, __shfl_xor(m, 1));
            m = fmaxf(m, __shfl_xor(m, 2));
            m = fmaxf(m, __shfl_xor(m, 4));
            m = fmaxf(m, __shfl_xor(m, 8));
            const float mn = fmaxf(m_r[r], m);
            float e[4];
#pragma unroll
            for (int b = 0; b < 4; ++b) e[b] = __expf(x[b] - mn);
            float ts = (e[0] + e[1]) + (e[2] + e[3]);
            ts += __shfl_xor(ts, 1);
            ts += __shfl_xor(ts, 2);
            ts += __shfl_xor(ts, 4);
            ts += __shfl_xor(ts, 8);
            alpha[r] = __expf(m_r[r] - mn);
            l_r[r] = l_r[r] * alpha[r] + ts;
            m_r[r] = mn;
#pragma unroll
            for (int b = 0; b < 4; ++b)
                Ps[w][(quad * 4 + r) * 72 + b * 16 + lr] = (_Float16)e[b];
        }

        // ---- O = O*alpha + P V ----
#pragma unroll
        for (int n = 0; n < 8; ++n)
#pragma unroll
            for (int r = 0; r < 4; ++r) Oacc[n][r] *= alpha[r];

        const half8 af0 = *(const half8*)&Ps[w][lr * 72 + quad * 8];
        const half8 af1 = *(const half8*)&Ps[w][lr * 72 + 32 + quad * 8];
        __builtin_amdgcn_s_setprio(1);
#pragma unroll
        for (int n = 0; n < 8; ++n) {
            const half8 bv0 = *(const half8*)&Vl[(n * 16 + lr) * 72 + quad * 8];
            const half8 bv1 = *(const half8*)&Vl[(n * 16 + lr) * 72 + 32 + quad * 8];
            Oacc[n] = __builtin_amdgcn_mfma_f32_16x16x32_f16(af0, bv0, Oacc[n], 0, 0, 0);
            Oacc[n] = __builtin_amdgcn_mfma_f32_16x16x32_f16(af1, bv1, Oacc[n], 0, 0, 0);
        }
        __builtin_amdgcn_s_setprio(0);
        __syncthreads();
    }

    // ---- normalize, LDS round-trip for coalesced f16 store ----
    float inv[4];
#pragma unroll
    for (int r = 0; r < 4; ++r) inv[r] = 1.f / l_r[r];
    _Float16* Ol = Kl;  // reuse (all K reads fenced by loop-end barrier)
#pragma unroll
    for (int n = 0; n < 8; ++n)
#pragma unroll
        for (int r = 0; r < 4; ++r)
            Ol[(w * 16 + quad * 4 + r) * 128 + n * 16 + lr] = (_Float16)(Oacc[n][r] * inv[r]);
    __syncthreads();
#pragma unroll
    for (int it = 0; it < 4; ++it) {
        const int idx = tid + it * 256;
        const int row = idx >> 4, c8 = idx & 15;   // 64 rows x 16 half8 groups
        *(half8*)(Aout + (size_t)(q0 + row) * DD + h * HDIM + c8 * 8) =
            *(const half8*)&Ol[row * 128 + c8 * 8];
    }
}

// ---------------------------------------------------------------------------
// Launch: 4 kernels (rope fused into attn). ws (f16, 4M elems = 8MB each):
// xh, Wqt, Wkt, Wvt, Wot, Qh, Kh, Vt = 64 MB. Attn output reuses xh.
// ---------------------------------------------------------------------------
extern "C" void kernel_launch(void* const* d_in, const int* in_sizes, int n_in,
                              void* d_out, int out_size, void* d_ws, size_t ws_size,
                              hipStream_t stream) {
    const float* x  = (const float*)d_in[0];
    const float* Wq = (const float*)d_in[1];
    const float* Wk = (const float*)d_in[2];
    const float* Wv = (const float*)d_in[3];
    const float* Wo = (const float*)d_in[4];
    const float* sn = (const float*)d_in[5];
    const float* cs = (const float*)d_in[6];
    const int* doc  = (const int*)d_in[7];
    float* out = (float*)d_out;

    const size_t NE = (size_t)TT * DD;
    _Float16* xh  = (_Float16*)d_ws;
    _Float16* Wqt = xh  + NE;
    _Float16* Wkt = Wqt + NE;
    _Float16* Wvt = Wkt + NE;
    _Float16* Wot = Wvt + NE;
    _Float16* Qh  = Wot + NE;
    _Float16* Kh  = Qh  + NE;
    _Float16* Vt  = Kh  + NE;
    _Float16* Abh = xh;  // reuse: xh consumed by qkv_gemm before attn writes

    const dim3 bb(256);

    prep_kernel<<<dim3(DD / 64, DD / 64, 5), bb, 0, stream>>>(x, Wq, Wk, Wv, Wo,
                                                              xh, Wqt, Wkt, Wvt, Wot);
    qkv_gemm_kernel<<<dim3(DD / 128, TT / 128, 3), bb, 0, stream>>>(xh, Wqt, Wkt, Wvt,
                                                                    Qh, Kh, Vt);
    attn_kernel<<<dim3(TT / 64, NH), bb, 0, stream>>>(Qh, Kh, Vt, sn, cs, doc, Abh);
    ogemm_kernel<<<dim3(DD / 128, TT / 64), bb, 0, stream>>>(Abh, Wot, out);
}